// Round 4
// baseline (58.833 us; speedup 1.0000x reference)
//
#include <hip/hip_runtime.h>

#define NPIX  65536
#define NG    512
#define NB    4
#define MAXD  362.03867196751236f
#define WRAD  24                  // Chebyshev window radius for term-2 fast path
#define WDIM  49                  // 2*WRAD+1
#define WCNT  2401                // WDIM*WDIM
#define SAFE_Q (23.0f - MAXD)     // block qm <= this => window provably contains global min
#define NBLK_T1 256
#define NBLK_T2 (NB*NG)           // 2048
#define NBLK_TOT (NBLK_T1 + NBLK_T2)
#define CNT_OFF 4096              // float index of completion counter in ws

// ws layout (floats):
//   [0,   256) : per-block partial sum of p*min_d  ([B][64])
//   [256, 512) : per-block partial sum of p        ([B][64])
//   [512, 2560): per-(b,g) min of p*(d - MAXD)     ([B][512])
//   [4096]     : completion counter (memset to 0 each call)

__device__ __forceinline__ float wave_sum(float v){
  #pragma unroll
  for (int o = 32; o > 0; o >>= 1) v += __shfl_down(v, o, 64);
  return v;
}
__device__ __forceinline__ float wave_min(float v){
  #pragma unroll
  for (int o = 32; o > 0; o >>= 1) v = fminf(v, __shfl_down(v, o, 64));
  return v;
}

__global__ __launch_bounds__(256) void k_fused(const float* __restrict__ prob,
                                               const int* __restrict__ gt,
                                               float* __restrict__ ws,
                                               float* __restrict__ out){
  const int tid = threadIdx.x;
  __shared__ float4 gsh[NG];     // term-1 gt staging (8 KB)
  __shared__ float red[8];
  __shared__ float t1sh[NB];
  __shared__ int   lastFlag;

  if (blockIdx.x < NBLK_T1){
    // ---------------- term 1: full pixel scan, 4 px/thread ----------------
    const int b   = blockIdx.x >> 6;
    const int blk = blockIdx.x & 63;

    const int2* gtp = ((const int2*)gt) + b*NG;
    for (int g = tid; g < NG; g += 256){
      const int2 q = gtp[g];
      const float ghf = (float)q.x, gwf = (float)q.y;
      gsh[g] = make_float4(-2.0f*ghf, -2.0f*gwf, fmaf(ghf, ghf, gwf*gwf), 0.0f);
    }
    __syncthreads();

    const int base = blk*1024 + tid*4;     // 4 consecutive pixels, same row
    const int h  = base >> 8;
    const int w0 = base & 255;
    const float hf  = (float)h;
    const float wf0 = (float)w0, wf1 = wf0+1.0f, wf2 = wf0+2.0f, wf3 = wf0+3.0f;

    float m0 = 3e38f, m1 = 3e38f, m2 = 3e38f, m3 = 3e38f;
    #pragma unroll 8
    for (int g = 0; g < NG; ++g){
      const float4 q = gsh[g];             // wave-uniform -> LDS broadcast
      const float t = fmaf(q.x, hf, q.z);  // c - 2*gh*h
      m0 = fminf(m0, fmaf(q.y, wf0, t));   // d2 - (h^2+w^2), exact int in fp32
      m1 = fminf(m1, fmaf(q.y, wf1, t));
      m2 = fminf(m2, fmaf(q.y, wf2, t));
      m3 = fminf(m3, fmaf(q.y, wf3, t));
    }

    const float4 p = *reinterpret_cast<const float4*>(prob + b*NPIX + base);
    const float s0 = (float)(h*h + (w0+0)*(w0+0));
    const float s1 = (float)(h*h + (w0+1)*(w0+1));
    const float s2 = (float)(h*h + (w0+2)*(w0+2));
    const float s3 = (float)(h*h + (w0+3)*(w0+3));
    const float d0 = __builtin_amdgcn_sqrtf(m0 + s0);
    const float d1 = __builtin_amdgcn_sqrtf(m1 + s1);
    const float d2 = __builtin_amdgcn_sqrtf(m2 + s2);
    const float d3 = __builtin_amdgcn_sqrtf(m3 + s3);

    float spd = fmaf(p.x, d0, fmaf(p.y, d1, fmaf(p.z, d2, p.w*d3)));
    float sp  = (p.x + p.y) + (p.z + p.w);

    spd = wave_sum(spd);
    sp  = wave_sum(sp);
    const int wid = tid >> 6, lane = tid & 63;
    if (lane == 0){ red[wid] = spd; red[4+wid] = sp; }
    __syncthreads();
    if (tid == 0){
      ws[blockIdx.x]       = (red[0]+red[1]) + (red[2]+red[3]);
      ws[256 + blockIdx.x] = (red[4]+red[5]) + (red[6]+red[7]);
    }
  } else {
    // ---------------- term 2: one (b,g) per block; window + exact fallback ----------------
    const int idx = blockIdx.x - NBLK_T1;  // b*NG + g
    const int b   = idx >> 9;
    const int gh  = gt[idx*2 + 0];
    const int gw  = gt[idx*2 + 1];

    float qm = 3e38f;
    for (int i = tid; i < WCNT; i += 256){
      const int r  = i / WDIM;
      const int c  = i - r*WDIM;
      const int hh = gh - WRAD + r;
      const int ww = gw - WRAD + c;
      if ((unsigned)hh < 256u && (unsigned)ww < 256u){
        const float p  = prob[b*NPIX + hh*256 + ww];
        const int  dh  = r - WRAD, dw = c - WRAD;
        const float d  = __builtin_amdgcn_sqrtf((float)(dh*dh + dw*dw));
        qm = fminf(qm, fmaf(p, d, p * (-MAXD)));
      }
    }
    qm = wave_min(qm);
    const int wid = tid >> 6, lane = tid & 63;
    if (lane == 0) red[wid] = qm;
    __syncthreads();
    float qf = fminf(fminf(red[0], red[1]), fminf(red[2], red[3]));

    if (qf > SAFE_Q){
      // exact fallback: full-image rescan (provably unreachable unless window
      // lacks any high-prob pixel; keeps kernel exact for arbitrary inputs)
      const float ghf = (float)gh, gwf = (float)gw;
      const float aa  = -2.0f*ghf;
      const float wf  = (float)tid;
      const float bc  = fmaf(-2.0f*gwf, wf, fmaf(ghf, ghf, gwf*gwf));
      const float wsq = wf*wf;
      float q2 = 3e38f;
      const float* pr = prob + b*NPIX + tid;
      #pragma unroll 4
      for (int i = 0; i < 256; ++i){
        const float p   = pr[i*256];
        const float hfi = (float)i;
        const float d2v = fmaf(aa, hfi, fmaf(hfi, hfi, wsq) + bc);
        const float d   = __builtin_amdgcn_sqrtf(d2v);
        q2 = fminf(q2, fmaf(p, d, p * (-MAXD)));
      }
      q2 = wave_min(q2);
      __syncthreads();
      if (lane == 0) red[wid] = q2;
      __syncthreads();
      qf = fminf(fminf(red[0], red[1]), fminf(red[2], red[3]));
    }
    if (tid == 0) ws[512 + idx] = qf;
  }

  // ---------------- last-block finish (deterministic reduction) ----------------
  __syncthreads();
  if (tid == 0){
    __threadfence();                                   // release partials (device scope)
    const unsigned p = atomicAdd((unsigned*)(ws + CNT_OFF), 1u);
    lastFlag = (p == NBLK_TOT - 1u);
  }
  __syncthreads();
  if (lastFlag){
    __threadfence();                                   // acquire all partials
    float s = 0.0f;
    #pragma unroll
    for (int k = 0; k < 8; ++k) s += ws[512 + tid + 256*k];
    s = wave_sum(s);
    const int wid = tid >> 6, lane = tid & 63;
    if (lane == 0) red[4 + wid] = s;
    __syncthreads();

    if (tid < NB){
      float pd = 0.0f, pp = 0.0f;
      for (int k = 0; k < 64; ++k){
        pd += ws[tid*64 + k];
        pp += ws[256 + tid*64 + k];
      }
      t1sh[tid] = pd / (pp + 1e-6f);
    }
    __syncthreads();

    if (tid == 0){
      const float s2    = (red[4]+red[5]) + (red[6]+red[7]);
      const float term2 = MAXD + s2 * (1.0f/2048.0f);
      const float term1 = ((t1sh[0]+t1sh[1]) + (t1sh[2]+t1sh[3])) * 0.25f;
      out[0] = term1 + term2;
    }
  }
}

extern "C" void kernel_launch(void* const* d_in, const int* in_sizes, int n_in,
                              void* d_out, int out_size, void* d_ws, size_t ws_size,
                              hipStream_t stream) {
  const float* prob = (const float*)d_in[0];
  const int*   gt   = (const int*)d_in[1];
  float* out = (float*)d_out;
  float* ws  = (float*)d_ws;

  hipMemsetAsync(ws + CNT_OFF, 0, 4, stream);          // reset completion counter
  hipLaunchKernelGGL(k_fused, dim3(NBLK_TOT), dim3(256), 0, stream, prob, gt, ws, out);
}

// Round 6
// 58.128 us; speedup vs baseline: 1.0121x; 1.0121x over previous
//
#include <hip/hip_runtime.h>

#define NPIX  65536
#define NG    512
#define NB    4
#define MAXD  362.03867196751236f
#define WRAD  24                  // Chebyshev window radius for term-2 fast path
#define WDIM  49                  // 2*WRAD+1
#define WCNT  2401                // WDIM*WDIM
#define SAFE_Q (23.0f - MAXD)     // window min <= this => provably global (outside: q >= 25-MAXD)
#define NBLK_T1 512               // term-1: 2 rows per block
#define NBLK_T2 (NB*NG)           // 2048
#define NBLK_MAIN (NBLK_T1 + NBLK_T2)

// ws layout (floats):
//   [0,    512) : term-1 per-block partial sum of p*min_d   (b = blk>>7)
//   [512, 1024) : term-1 per-block partial sum of p
//   [1024,3072) : per-(b,g) min of p*(d - MAXD)
//   [4096,12288): gabc float4[2048]: (-2gh, -2gw, gh^2+gw^2, 0)

__device__ __forceinline__ float wave_sum(float v){
  #pragma unroll
  for (int o = 32; o > 0; o >>= 1) v += __shfl_down(v, o, 64);
  return v;
}
__device__ __forceinline__ float wave_min(float v){
  #pragma unroll
  for (int o = 32; o > 0; o >>= 1) v = fminf(v, __shfl_down(v, o, 64));
  return v;
}

// ---------- prep: gabc from gt ----------
__global__ __launch_bounds__(256) void k_prep(const int* __restrict__ gt,
                                              float4* __restrict__ gabc){
  const int idx = blockIdx.x*256 + threadIdx.x;     // 0..2047
  const int gh = gt[idx*2 + 0];
  const int gw = gt[idx*2 + 1];
  const float ghf = (float)gh, gwf = (float)gw;
  gabc[idx] = make_float4(-2.0f*ghf, -2.0f*gwf, fmaf(ghf, ghf, gwf*gwf), 0.0f);
}

// ---------- main: term-1 (blocks 0..511) + term-2 windows (blocks 512..2559) ----------
__global__ __launch_bounds__(256) void k_main(const float* __restrict__ prob,
                                              const int* __restrict__ gt,
                                              const float4* __restrict__ gabc,
                                              float* __restrict__ wsout){
  const int tid = threadIdx.x;
  __shared__ float red[8];

  if (blockIdx.x < NBLK_T1){
    // ----- term 1: block = (b, row-pair); thread = column; g-data via uniform loads -----
    const int b  = blockIdx.x >> 7;                 // 128 blocks per image
    const int hp = (blockIdx.x & 127) << 1;         // rows hp, hp+1
    const float hf0 = (float)hp, hf1 = (float)(hp + 1);
    const float wf  = (float)tid;

    const float4* __restrict__ gq = gabc + b*NG;    // block-uniform address stream

    float m0 = 3e38f, m1 = 3e38f;
    for (int g0 = 0; g0 < NG; g0 += 8){
      #pragma unroll
      for (int j = 0; j < 8; ++j){
        const float4 q = gq[g0 + j];                // uniform -> s_load (SGPR broadcast)
        const float t0 = fmaf(q.x, hf0, q.z);       // c - 2*gh*h   (exact int in fp32)
        const float t1 = fmaf(q.x, hf1, q.z);
        m0 = fminf(m0, fmaf(q.y, wf, t0));          // d2 - (h^2+w^2), exact
        m1 = fminf(m1, fmaf(q.y, wf, t1));
      }
    }

    const float s0 = (float)(hp*hp + tid*tid);
    const float s1 = (float)((hp+1)*(hp+1) + tid*tid);
    const float d0 = __builtin_amdgcn_sqrtf(m0 + s0);
    const float d1 = __builtin_amdgcn_sqrtf(m1 + s1);

    const float p0 = prob[b*NPIX + hp*256 + tid];         // coalesced
    const float p1 = prob[b*NPIX + hp*256 + 256 + tid];

    float spd = fmaf(p0, d0, p1*d1);
    float sp  = p0 + p1;

    spd = wave_sum(spd);
    sp  = wave_sum(sp);
    const int wid = tid >> 6, lane = tid & 63;
    if (lane == 0){ red[wid] = spd; red[4+wid] = sp; }
    __syncthreads();
    if (tid == 0){
      wsout[blockIdx.x]       = (red[0]+red[1]) + (red[2]+red[3]);
      wsout[512 + blockIdx.x] = (red[4]+red[5]) + (red[6]+red[7]);
    }
  } else {
    // ----- term 2: one (b,g) per block; window + exact in-block fallback -----
    const int idx = blockIdx.x - NBLK_T1;           // b*NG + g
    const int b   = idx >> 9;
    const int gh  = gt[idx*2 + 0];
    const int gw  = gt[idx*2 + 1];

    float qm = 3e38f;
    for (int i = tid; i < WCNT; i += 256){
      const int r  = i / WDIM;
      const int c  = i - r*WDIM;
      const int hh = gh - WRAD + r;
      const int ww = gw - WRAD + c;
      if ((unsigned)hh < 256u && (unsigned)ww < 256u){
        const float p  = prob[b*NPIX + hh*256 + ww];
        const int  dh  = r - WRAD, dw = c - WRAD;
        const float d  = __builtin_amdgcn_sqrtf((float)(dh*dh + dw*dw));
        qm = fminf(qm, fmaf(p, d, p * (-MAXD)));
      }
    }
    qm = wave_min(qm);
    const int wid = tid >> 6, lane = tid & 63;
    if (lane == 0) red[wid] = qm;
    __syncthreads();
    float qf = fminf(fminf(red[0], red[1]), fminf(red[2], red[3]));

    if (qf > SAFE_Q){
      // exact fallback: full-image rescan (block-uniform branch; practically never
      // taken on real data, keeps the kernel exact for arbitrary inputs)
      const float ghf = (float)gh, gwf = (float)gw;
      const float aa  = -2.0f*ghf;
      const float wf  = (float)tid;
      const float bc  = fmaf(-2.0f*gwf, wf, fmaf(ghf, ghf, gwf*gwf));
      const float wsq = wf*wf;
      float q2 = 3e38f;
      const float* pr = prob + b*NPIX + tid;
      #pragma unroll 4
      for (int i = 0; i < 256; ++i){
        const float p   = pr[i*256];
        const float hfi = (float)i;
        const float d2v = fmaf(aa, hfi, fmaf(hfi, hfi, wsq) + bc);
        const float d   = __builtin_amdgcn_sqrtf(d2v);
        q2 = fminf(q2, fmaf(p, d, p * (-MAXD)));
      }
      q2 = wave_min(q2);
      __syncthreads();
      if (lane == 0) red[wid] = q2;
      __syncthreads();
      qf = fminf(fminf(red[0], red[1]), fminf(red[2], red[3]));
    }
    if (tid == 0) wsout[1024 + idx] = qf;
  }
}

// ---------- finish: deterministic reduction to scalar ----------
__global__ __launch_bounds__(256) void k_finish(const float* __restrict__ ws,
                                                float* __restrict__ out){
  const int tid = threadIdx.x;
  __shared__ float red[4];
  __shared__ float t1sh[NB];

  // term-2: sum the 2048 per-(b,g) mins
  float s = 0.0f;
  #pragma unroll
  for (int k = 0; k < 8; ++k) s += ws[1024 + tid + 256*k];
  s = wave_sum(s);
  const int wid = tid >> 6, lane = tid & 63;
  if (lane == 0) red[wid] = s;
  __syncthreads();

  // term-1: per-image sums over 128 blocks
  if (tid < NB){
    float pd = 0.0f, pp = 0.0f;
    for (int k = 0; k < 128; ++k){
      pd += ws[tid*128 + k];
      pp += ws[512 + tid*128 + k];
    }
    t1sh[tid] = pd / (pp + 1e-6f);
  }
  __syncthreads();

  if (tid == 0){
    const float s2    = (red[0]+red[1]) + (red[2]+red[3]);
    const float term2 = MAXD + s2 * (1.0f/2048.0f);
    const float term1 = ((t1sh[0]+t1sh[1]) + (t1sh[2]+t1sh[3])) * 0.25f;
    out[0] = term1 + term2;
  }
}

extern "C" void kernel_launch(void* const* d_in, const int* in_sizes, int n_in,
                              void* d_out, int out_size, void* d_ws, size_t ws_size,
                              hipStream_t stream) {
  const float* prob = (const float*)d_in[0];
  const int*   gt   = (const int*)d_in[1];
  float* out  = (float*)d_out;
  float* ws   = (float*)d_ws;
  float4* gabc = (float4*)(ws + 4096);

  hipLaunchKernelGGL(k_prep,   dim3(8),         dim3(256), 0, stream, gt, gabc);
  hipLaunchKernelGGL(k_main,   dim3(NBLK_MAIN), dim3(256), 0, stream, prob, gt, (const float4*)gabc, ws);
  hipLaunchKernelGGL(k_finish, dim3(1),         dim3(256), 0, stream, ws, out);
}

// Round 7
// 35.975 us; speedup vs baseline: 1.6354x; 1.6158x over previous
//
#include <hip/hip_runtime.h>

#define NPIX  65536
#define NG    512
#define NB    4
#define MAXD  362.03867196751236f
#define WRAD  24                  // Chebyshev window radius for term-2 fast path
#define WDIM  49                  // 2*WRAD+1
#define WCNT  2401                // WDIM*WDIM
#define SAFE_Q (23.0f - MAXD)     // window min <= this => provably global (outside: q >= 25-MAXD)
#define NBLK_T1 512               // term-1: 2 rows per block
#define NBLK_T2 (NB*NG)           // 2048
#define NBLK_MAIN (NBLK_T1 + NBLK_T2)

// ws layout (floats):
//   [0,    512) : term-1 per-block partial sum of p*min_d   (b = blk>>7)
//   [512, 1024) : term-1 per-block partial sum of p
//   [1024,3072) : per-(b,g) min of p*(d - MAXD)
//   [4096,12288): gabc float4[2048]: (-2gh, -2gw, gh^2+gw^2, 0)

__device__ __forceinline__ float wave_sum(float v){
  #pragma unroll
  for (int o = 32; o > 0; o >>= 1) v += __shfl_down(v, o, 64);
  return v;
}
__device__ __forceinline__ float wave_min(float v){
  #pragma unroll
  for (int o = 32; o > 0; o >>= 1) v = fminf(v, __shfl_down(v, o, 64));
  return v;
}
__device__ __forceinline__ float bcast_lane(float v, int k){
  return __uint_as_float(__builtin_amdgcn_readlane(__float_as_uint(v), k));
}

// ---------- prep: gabc from gt ----------
__global__ __launch_bounds__(256) void k_prep(const int* __restrict__ gt,
                                              float4* __restrict__ gabc){
  const int idx = blockIdx.x*256 + threadIdx.x;     // 0..2047
  const int gh = gt[idx*2 + 0];
  const int gw = gt[idx*2 + 1];
  const float ghf = (float)gh, gwf = (float)gw;
  gabc[idx] = make_float4(-2.0f*ghf, -2.0f*gwf, fmaf(ghf, ghf, gwf*gwf), 0.0f);
}

// ---------- main: term-1 (blocks 0..511) + term-2 windows (blocks 512..2559) ----------
__global__ __launch_bounds__(256) void k_main(const float* __restrict__ prob,
                                              const int* __restrict__ gt,
                                              const float4* __restrict__ gabc,
                                              float* __restrict__ wsout){
  const int tid = threadIdx.x;
  __shared__ float red[8];

  if (blockIdx.x < NBLK_T1){
    // ----- term 1: block = (b, row-pair); thread = column -----
    // g-constants: 64 per wave-batch via ONE coalesced dwordx4 load (lane g),
    // then v_readlane SGPR-broadcast to all lanes. 8 loads/wave total; no LDS.
    const int b  = blockIdx.x >> 7;                 // 128 blocks per image
    const int hp = (blockIdx.x & 127) << 1;         // rows hp, hp+1
    const float hf0 = (float)hp, hf1 = (float)(hp + 1);
    const float wf  = (float)tid;
    const int  lane = tid & 63;

    const float4* __restrict__ gq = gabc + b*NG;

    float m0 = 3e38f, m1 = 3e38f;
    #pragma unroll 1
    for (int g0 = 0; g0 < NG; g0 += 64){
      const float4 q = gq[g0 + lane];               // coalesced, 1 KB per wave
      #pragma unroll 64
      for (int k = 0; k < 64; ++k){
        const float sa = bcast_lane(q.x, k);        // -2*gh
        const float sb = bcast_lane(q.y, k);        // -2*gw
        const float sc = bcast_lane(q.z, k);        // gh^2+gw^2
        const float t0 = fmaf(sa, hf0, sc);         // c - 2*gh*h   (exact int in fp32)
        const float t1 = fmaf(sa, hf1, sc);
        m0 = fminf(m0, fmaf(sb, wf, t0));           // d2 - (h^2+w^2), exact
        m1 = fminf(m1, fmaf(sb, wf, t1));
      }
    }

    const float s0 = (float)(hp*hp + tid*tid);
    const float s1 = (float)((hp+1)*(hp+1) + tid*tid);
    const float d0 = __builtin_amdgcn_sqrtf(m0 + s0);
    const float d1 = __builtin_amdgcn_sqrtf(m1 + s1);

    const float p0 = prob[b*NPIX + hp*256 + tid];         // coalesced
    const float p1 = prob[b*NPIX + hp*256 + 256 + tid];

    float spd = fmaf(p0, d0, p1*d1);
    float sp  = p0 + p1;

    spd = wave_sum(spd);
    sp  = wave_sum(sp);
    const int wid = tid >> 6;
    if (lane == 0){ red[wid] = spd; red[4+wid] = sp; }
    __syncthreads();
    if (tid == 0){
      wsout[blockIdx.x]       = (red[0]+red[1]) + (red[2]+red[3]);
      wsout[512 + blockIdx.x] = (red[4]+red[5]) + (red[6]+red[7]);
    }
  } else {
    // ----- term 2: one (b,g) per block; window + exact in-block fallback -----
    const int idx = blockIdx.x - NBLK_T1;           // b*NG + g
    const int b   = idx >> 9;
    const int gh  = gt[idx*2 + 0];
    const int gw  = gt[idx*2 + 1];

    float qm = 3e38f;
    for (int i = tid; i < WCNT; i += 256){
      const int r  = i / WDIM;
      const int c  = i - r*WDIM;
      const int hh = gh - WRAD + r;
      const int ww = gw - WRAD + c;
      if ((unsigned)hh < 256u && (unsigned)ww < 256u){
        const float p  = prob[b*NPIX + hh*256 + ww];
        const int  dh  = r - WRAD, dw = c - WRAD;
        const float d  = __builtin_amdgcn_sqrtf((float)(dh*dh + dw*dw));
        qm = fminf(qm, fmaf(p, d, p * (-MAXD)));
      }
    }
    qm = wave_min(qm);
    const int wid = tid >> 6, lane = tid & 63;
    if (lane == 0) red[wid] = qm;
    __syncthreads();
    float qf = fminf(fminf(red[0], red[1]), fminf(red[2], red[3]));

    if (qf > SAFE_Q){
      // exact fallback: full-image rescan (block-uniform branch; practically never
      // taken on real data, keeps the kernel exact for arbitrary inputs)
      const float ghf = (float)gh, gwf = (float)gw;
      const float aa  = -2.0f*ghf;
      const float wf  = (float)tid;
      const float bc  = fmaf(-2.0f*gwf, wf, fmaf(ghf, ghf, gwf*gwf));
      const float wsq = wf*wf;
      float q2 = 3e38f;
      const float* pr = prob + b*NPIX + tid;
      #pragma unroll 4
      for (int i = 0; i < 256; ++i){
        const float p   = pr[i*256];
        const float hfi = (float)i;
        const float d2v = fmaf(aa, hfi, fmaf(hfi, hfi, wsq) + bc);
        const float d   = __builtin_amdgcn_sqrtf(d2v);
        q2 = fminf(q2, fmaf(p, d, p * (-MAXD)));
      }
      q2 = wave_min(q2);
      __syncthreads();
      if (lane == 0) red[wid] = q2;
      __syncthreads();
      qf = fminf(fminf(red[0], red[1]), fminf(red[2], red[3]));
    }
    if (tid == 0) wsout[1024 + idx] = qf;
  }
}

// ---------- finish: deterministic reduction to scalar ----------
__global__ __launch_bounds__(256) void k_finish(const float* __restrict__ ws,
                                                float* __restrict__ out){
  const int tid = threadIdx.x;
  __shared__ float red[4];
  __shared__ float t1sh[NB];

  // term-2: sum the 2048 per-(b,g) mins
  float s = 0.0f;
  #pragma unroll
  for (int k = 0; k < 8; ++k) s += ws[1024 + tid + 256*k];
  s = wave_sum(s);
  const int wid = tid >> 6, lane = tid & 63;
  if (lane == 0) red[wid] = s;
  __syncthreads();

  // term-1: per-image sums over 128 blocks
  if (tid < NB){
    float pd = 0.0f, pp = 0.0f;
    for (int k = 0; k < 128; ++k){
      pd += ws[tid*128 + k];
      pp += ws[512 + tid*128 + k];
    }
    t1sh[tid] = pd / (pp + 1e-6f);
  }
  __syncthreads();

  if (tid == 0){
    const float s2    = (red[0]+red[1]) + (red[2]+red[3]);
    const float term2 = MAXD + s2 * (1.0f/2048.0f);
    const float term1 = ((t1sh[0]+t1sh[1]) + (t1sh[2]+t1sh[3])) * 0.25f;
    out[0] = term1 + term2;
  }
}

extern "C" void kernel_launch(void* const* d_in, const int* in_sizes, int n_in,
                              void* d_out, int out_size, void* d_ws, size_t ws_size,
                              hipStream_t stream) {
  const float* prob = (const float*)d_in[0];
  const int*   gt   = (const int*)d_in[1];
  float* out  = (float*)d_out;
  float* ws   = (float*)d_ws;
  float4* gabc = (float4*)(ws + 4096);

  hipLaunchKernelGGL(k_prep,   dim3(8),         dim3(256), 0, stream, gt, gabc);
  hipLaunchKernelGGL(k_main,   dim3(NBLK_MAIN), dim3(256), 0, stream, prob, gt, (const float4*)gabc, ws);
  hipLaunchKernelGGL(k_finish, dim3(1),         dim3(256), 0, stream, ws, out);
}

// Round 9
// 27.649 us; speedup vs baseline: 2.1278x; 1.3011x over previous
//
#include <hip/hip_runtime.h>

#define NPIX  65536
#define NG    512
#define NB    4
#define MAXD  362.03867196751236f
#define WRAD  24                  // Chebyshev window radius for term-2 fast path
#define WDIM  49                  // 2*WRAD+1
#define WCNT  2401                // WDIM*WDIM
#define SAFE_Q (23.0f - MAXD)     // window min <= this => provably global
#define NBLK_T1 128               // term-1: 8 rows per block (4 img x 32 row-groups)
#define NBLK_T2 (NB*NG)           // 2048
#define NBLK_MAIN (NBLK_T1 + NBLK_T2)

// ws layout (floats):
//   [0,   128) : term-1 per-block partial sum of p*min_d   (b = blk>>5)
//   [512, 640) : term-1 per-block partial sum of p
//   [1024,3072): per-(b,g) min of p*(d - MAXD)

__device__ __forceinline__ float wave_sum(float v){
  #pragma unroll
  for (int o = 32; o > 0; o >>= 1) v += __shfl_down(v, o, 64);
  return v;
}
__device__ __forceinline__ float wave_min(float v){
  #pragma unroll
  for (int o = 32; o > 0; o >>= 1) v = fminf(v, __shfl_down(v, o, 64));
  return v;
}

// ---------- main: term-1 (blocks 0..127) + term-2 windows (blocks 128..2175) ----------
__global__ __launch_bounds__(256) void k_main(const float* __restrict__ prob,
                                              const int* __restrict__ gt,
                                              float* __restrict__ wsout){
  const int tid = threadIdx.x;

  if (blockIdx.x < NBLK_T1){
    // ----- term 1: block = (b, 8-row group); thread = column -----
    // transport: (sa,sb)=(-2gh,-2gw) in LDS (4KB), ds_read_b64 broadcast per g;
    // sc = (sa^2+sb^2)/4 reconstructed in-register (exact ints < 2^24).
    __shared__ float2 gsab[NG];
    __shared__ float red[8];
    const int b  = blockIdx.x >> 5;                 // 32 blocks per image
    const int hp = (blockIdx.x & 31) << 3;          // rows hp .. hp+7
    const float wf = (float)tid;

    const int2* gtp = ((const int2*)gt) + b*NG;
    #pragma unroll
    for (int s = 0; s < 2; ++s){
      const int g = tid + 256*s;
      const int2 q = gtp[g];
      gsab[g] = make_float2(-2.0f*(float)q.x, -2.0f*(float)q.y);
    }
    __syncthreads();

    float hf[8], m[8];
    #pragma unroll
    for (int r = 0; r < 8; ++r){ hf[r] = (float)(hp + r); m[r] = 3e38f; }

    #pragma unroll 8
    for (int g = 0; g < NG; ++g){
      const float2 q = gsab[g];                     // wave-uniform b64 broadcast
      float sc = q.x*q.x;
      sc = fmaf(q.y, q.y, sc) * 0.25f;              // gh^2+gw^2, exact
      const float u = fmaf(q.y, wf, sc);            // sc - 2*gw*w, exact int
      #pragma unroll
      for (int r = 0; r < 8; ++r)
        m[r] = fminf(m[r], fmaf(q.x, hf[r], u));    // d2 - (h^2+w^2), exact
    }

    float spd = 0.0f, sp = 0.0f;
    const float w2 = (float)(tid*tid);
    #pragma unroll
    for (int r = 0; r < 8; ++r){
      const float d = __builtin_amdgcn_sqrtf(m[r] + fmaf(hf[r], hf[r], w2));
      const float p = prob[b*NPIX + (hp + r)*256 + tid];   // coalesced
      spd = fmaf(p, d, spd);
      sp += p;
    }

    spd = wave_sum(spd);
    sp  = wave_sum(sp);
    const int wid = tid >> 6, lane = tid & 63;
    if (lane == 0){ red[wid] = spd; red[4+wid] = sp; }
    __syncthreads();
    if (tid == 0){
      wsout[blockIdx.x]       = (red[0]+red[1]) + (red[2]+red[3]);
      wsout[512 + blockIdx.x] = (red[4]+red[5]) + (red[6]+red[7]);
    }
  } else {
    // ----- term 2: one (b,g) per block; window + exact in-block fallback -----
    __shared__ float red[8];
    const int idx = blockIdx.x - NBLK_T1;           // b*NG + g
    const int b   = idx >> 9;
    const int gh  = gt[idx*2 + 0];
    const int gw  = gt[idx*2 + 1];

    float qm = 3e38f;
    for (int i = tid; i < WCNT; i += 256){
      const int r  = i / WDIM;
      const int c  = i - r*WDIM;
      const int hh = gh - WRAD + r;
      const int ww = gw - WRAD + c;
      if ((unsigned)hh < 256u && (unsigned)ww < 256u){
        const float p  = prob[b*NPIX + hh*256 + ww];
        const int  dh  = r - WRAD, dw = c - WRAD;
        const float d  = __builtin_amdgcn_sqrtf((float)(dh*dh + dw*dw));
        qm = fminf(qm, fmaf(p, d, p * (-MAXD)));
      }
    }
    qm = wave_min(qm);
    const int wid = tid >> 6, lane = tid & 63;
    if (lane == 0) red[wid] = qm;
    __syncthreads();
    float qf = fminf(fminf(red[0], red[1]), fminf(red[2], red[3]));

    if (qf > SAFE_Q){
      // exact fallback: full-image rescan (block-uniform branch; practically never
      // taken on real data, keeps the kernel exact for arbitrary inputs)
      const float ghf = (float)gh, gwf = (float)gw;
      const float aa  = -2.0f*ghf;
      const float wf  = (float)tid;
      const float bc  = fmaf(-2.0f*gwf, wf, fmaf(ghf, ghf, gwf*gwf));
      const float wsq = wf*wf;
      float q2 = 3e38f;
      const float* pr = prob + b*NPIX + tid;
      #pragma unroll 4
      for (int i = 0; i < 256; ++i){
        const float p   = pr[i*256];
        const float hfi = (float)i;
        const float d2v = fmaf(aa, hfi, fmaf(hfi, hfi, wsq) + bc);
        const float d   = __builtin_amdgcn_sqrtf(d2v);
        q2 = fminf(q2, fmaf(p, d, p * (-MAXD)));
      }
      q2 = wave_min(q2);
      __syncthreads();
      if (lane == 0) red[wid] = q2;
      __syncthreads();
      qf = fminf(fminf(red[0], red[1]), fminf(red[2], red[3]));
    }
    if (tid == 0) wsout[1024 + idx] = qf;
  }
}

// ---------- finish: deterministic reduction to scalar ----------
__global__ __launch_bounds__(256) void k_finish(const float* __restrict__ ws,
                                                float* __restrict__ out){
  const int tid = threadIdx.x;
  __shared__ float red[4];
  __shared__ float t1sh[NB];

  // term-2: sum the 2048 per-(b,g) mins
  float s = 0.0f;
  #pragma unroll
  for (int k = 0; k < 8; ++k) s += ws[1024 + tid + 256*k];
  s = wave_sum(s);
  const int wid = tid >> 6, lane = tid & 63;
  if (lane == 0) red[wid] = s;
  __syncthreads();

  // term-1: per-image sums over 32 blocks
  if (tid < NB){
    float pd = 0.0f, pp = 0.0f;
    for (int k = 0; k < 32; ++k){
      pd += ws[tid*32 + k];
      pp += ws[512 + tid*32 + k];
    }
    t1sh[tid] = pd / (pp + 1e-6f);
  }
  __syncthreads();

  if (tid == 0){
    const float s2    = (red[0]+red[1]) + (red[2]+red[3]);
    const float term2 = MAXD + s2 * (1.0f/2048.0f);
    const float term1 = ((t1sh[0]+t1sh[1]) + (t1sh[2]+t1sh[3])) * 0.25f;
    out[0] = term1 + term2;
  }
}

extern "C" void kernel_launch(void* const* d_in, const int* in_sizes, int n_in,
                              void* d_out, int out_size, void* d_ws, size_t ws_size,
                              hipStream_t stream) {
  const float* prob = (const float*)d_in[0];
  const int*   gt   = (const int*)d_in[1];
  float* out = (float*)d_out;
  float* ws  = (float*)d_ws;

  hipLaunchKernelGGL(k_main,   dim3(NBLK_MAIN), dim3(256), 0, stream, prob, gt, ws);
  hipLaunchKernelGGL(k_finish, dim3(1),         dim3(256), 0, stream, ws, out);
}